// Round 8
// baseline (1258.165 us; speedup 1.0000x reference)
//
#include <hip/hip_runtime.h>

#define LTOT 5440
#define NTOK 21760   // B*L = 4*5440

typedef float  f32x4  __attribute__((ext_vector_type(4)));
typedef float  f32x2  __attribute__((ext_vector_type(2)));
typedef short  short8 __attribute__((ext_vector_type(8)));

__device__ __forceinline__ unsigned short f2bf(float f) {
  unsigned int u = __float_as_uint(f);
  u += 0x7FFF + ((u >> 16) & 1);          // RNE
  return (unsigned short)(u >> 16);
}

#define GLL16(gp, lp) __builtin_amdgcn_global_load_lds( \
    (const __attribute__((address_space(1))) void*)(gp), \
    (__attribute__((address_space(3))) void*)(lp), 16, 0, 0)

// ---------------------------------------------------------------------------
// Weight convert+transpose: all six weight kinds, all 6 layers -> bf16 [N][K]
// per-layer (elements): off[256][256]@0, attn[128][256]@65536  (together =
// fused offattn [384][256]@0), val[256][256]@98304, out[256][256]@163840,
// ff1[1024][256]@229376, ff2[256][1024]@491520 ; layer stride 753664.
// ---------------------------------------------------------------------------
__global__ void wconv(const float* __restrict__ w_off, const float* __restrict__ w_attn,
                      const float* __restrict__ w_val, const float* __restrict__ w_out,
                      const float* __restrict__ w_ff1, const float* __restrict__ w_ff2,
                      unsigned short* __restrict__ dst) {
  int tid = blockIdx.x * 256 + threadIdx.x;
  const int PER = 753664;
  if (tid >= 6 * PER) return;
  int layer = tid / PER;
  int rem = tid - layer * PER;
  int base, K, N;
  const float* src;
  if (rem < 65536)       { base = 0;      K = 256;  N = 256;  src = w_off; }
  else if (rem < 98304)  { base = 65536;  K = 256;  N = 128;  src = w_attn; }
  else if (rem < 163840) { base = 98304;  K = 256;  N = 256;  src = w_val; }
  else if (rem < 229376) { base = 163840; K = 256;  N = 256;  src = w_out; }
  else if (rem < 491520) { base = 229376; K = 256;  N = 1024; src = w_ff1; }
  else                   { base = 491520; K = 1024; N = 256;  src = w_ff2; }
  int local = rem - base;
  int n = local / K, k = local - n * K;
  dst[tid] = f2bf(src[(size_t)layer * K * N + (size_t)k * N + n]);
}

// pack fused off+attn bias: fb[layer][384]
__global__ void bpack(const float* __restrict__ b_off, const float* __restrict__ b_attn,
                      float* __restrict__ fb) {
  int l = blockIdx.x, t = threadIdx.x;
  fb[l * 384 + t] = (t < 256) ? b_off[l * 256 + t] : b_attn[l * 128 + t - 256];
}

// x = src (f32 master) + bf16 shadow + qb = bf16(src + pos + lev_emb)
__global__ void prep(const float* __restrict__ src, const float* __restrict__ pos,
                     const float* __restrict__ lev_emb, float* __restrict__ x,
                     unsigned short* __restrict__ xb, unsigned short* __restrict__ qb) {
  int i = blockIdx.x * 256 + threadIdx.x;   // float4 index, NTOK*64 total
  int d4 = i & 63;
  int tok = (i >> 6) % LTOT;
  int lev = (tok < 64) ? 0 : (tok < 320) ? 1 : (tok < 1344) ? 2 : 3;
  float4 s = ((const float4*)src)[i];
  float4 pv = ((const float4*)pos)[i];
  float4 lv = ((const float4*)lev_emb)[lev * 64 + d4];
  ((float4*)x)[i] = s;
  ushort4 o;
  o.x = f2bf(s.x); o.y = f2bf(s.y); o.z = f2bf(s.z); o.w = f2bf(s.w);
  ((ushort4*)xb)[i] = o;
  ushort4 q;
  q.x = f2bf(s.x + pv.x + lv.x);
  q.y = f2bf(s.y + pv.y + lv.y);
  q.z = f2bf(s.z + pv.z + lv.z);
  q.w = f2bf(s.w + pv.w + lv.w);
  ((ushort4*)qb)[i] = q;
}

// ---------------------------------------------------------------------------
// bf16 MFMA GEMM, C = A[M][K] * Wt[N][K]^T + bias.  TN, 128x128 tile, BK=32,
// DOUBLE-BUFFERED 2-phase: stage(next) issued before compute(cur), single
// __syncthreads per iter (its vmcnt(0) drains next-tile loads whose latency
// elapsed under compute). LDS 32KB (same as 1-phase BK=64). 4 waves 2x2.
// ---------------------------------------------------------------------------
template<bool RELU, bool OBF16>
__global__ __launch_bounds__(256) void gemm_tn(
    const unsigned short* __restrict__ A, const unsigned short* __restrict__ Wt,
    const float* __restrict__ bias, void* __restrict__ Cout,
    int M, int N, int K) {
  __shared__ __align__(16) unsigned short a_lds[2][128 * 32];
  __shared__ __align__(16) unsigned short b_lds[2][128 * 32];
  int m0 = blockIdx.x * 128;
  int n0 = blockIdx.y * 128;
  int t = threadIdx.x;
  int w = t >> 6, l = t & 63;
  int wr = (w >> 1) * 64, wc = (w & 1) * 64;
  int lr = l & 15, lk = (l >> 4) * 8;

  f32x4 acc[4][4] = {};
  int nt = K >> 5;
  int cur = 0;

  // prologue: stage tile 0 into buf 0
#pragma unroll
  for (int i = 0; i < 2; ++i) {
    int c = i * 256 + t;
    int row = c >> 2, s8 = (c & 3) * 8;
    GLL16(A + (size_t)(m0 + row) * K + s8, a_lds[0] + c * 8);
  }
#pragma unroll
  for (int i = 0; i < 2; ++i) {
    int c = i * 256 + t;
    int row = c >> 2, s8 = (c & 3) * 8;
    GLL16(Wt + (size_t)(n0 + row) * K + s8, b_lds[0] + c * 8);
  }
  __syncthreads();

  for (int tt = 0; tt < nt; ++tt) {
    if (tt + 1 < nt) {
      int k0 = (tt + 1) << 5;
      int nxt = cur ^ 1;
#pragma unroll
      for (int i = 0; i < 2; ++i) {
        int c = i * 256 + t;
        int row = c >> 2, s8 = (c & 3) * 8;
        GLL16(A + (size_t)(m0 + row) * K + k0 + s8, a_lds[nxt] + c * 8);
      }
#pragma unroll
      for (int i = 0; i < 2; ++i) {
        int c = i * 256 + t;
        int row = c >> 2, s8 = (c & 3) * 8;
        GLL16(Wt + (size_t)(n0 + row) * K + k0 + s8, b_lds[nxt] + c * 8);
      }
    }
    short8 af[4], bfr[4];
#pragma unroll
    for (int m = 0; m < 4; ++m)
      af[m] = *(const short8*)(a_lds[cur] + (wr + m * 16 + lr) * 32 + lk);
#pragma unroll
    for (int n = 0; n < 4; ++n)
      bfr[n] = *(const short8*)(b_lds[cur] + (wc + n * 16 + lr) * 32 + lk);
#pragma unroll
    for (int m = 0; m < 4; ++m)
#pragma unroll
      for (int n = 0; n < 4; ++n)
        acc[m][n] = __builtin_amdgcn_mfma_f32_16x16x32_bf16(af[m], bfr[n], acc[m][n], 0, 0, 0);
    __syncthreads();
    cur ^= 1;
  }

  int rb = (l >> 4) * 4;
#pragma unroll
  for (int n = 0; n < 4; ++n) {
    int col = n0 + wc + n * 16 + lr;
    float bv = bias[col];
#pragma unroll
    for (int m = 0; m < 4; ++m) {
#pragma unroll
      for (int r = 0; r < 4; ++r) {
        int row = m0 + wr + m * 16 + rb + r;
        float v = acc[m][n][r] + bv;
        if (RELU) v = fmaxf(v, 0.0f);
        if (OBF16) ((unsigned short*)Cout)[(size_t)row * N + col] = f2bf(v);
        else       ((float*)Cout)[(size_t)row * N + col] = v;
      }
    }
  }
}

// ---------------------------------------------------------------------------
// gemm_tn64: BM=64 x BN=128, BK=32 double-buffered 2-phase (24KB LDS).
// grid (340,2) for N=256 outputs. 4 waves 2x2, each 32x64 out.
// ---------------------------------------------------------------------------
template<bool RELU, bool OBF16>
__global__ __launch_bounds__(256) void gemm_tn64(
    const unsigned short* __restrict__ A, const unsigned short* __restrict__ Wt,
    const float* __restrict__ bias, void* __restrict__ Cout,
    int M, int N, int K) {
  __shared__ __align__(16) unsigned short a_lds[2][64 * 32];
  __shared__ __align__(16) unsigned short b_lds[2][128 * 32];
  int m0 = blockIdx.x * 64;
  int n0 = blockIdx.y * 128;
  int t = threadIdx.x;
  int w = t >> 6, l = t & 63;
  int wr = (w >> 1) * 32, wc = (w & 1) * 64;
  int lr = l & 15, lk = (l >> 4) * 8;

  f32x4 acc[2][4] = {};
  int nt = K >> 5;
  int cur = 0;

  {
    int row = t >> 2, s8 = (t & 3) * 8;
    GLL16(A + (size_t)(m0 + row) * K + s8, a_lds[0] + t * 8);
#pragma unroll
    for (int i = 0; i < 2; ++i) {
      int c = i * 256 + t;
      int rw = c >> 2, sb = (c & 3) * 8;
      GLL16(Wt + (size_t)(n0 + rw) * K + sb, b_lds[0] + c * 8);
    }
  }
  __syncthreads();

  for (int tt = 0; tt < nt; ++tt) {
    if (tt + 1 < nt) {
      int k0 = (tt + 1) << 5;
      int nxt = cur ^ 1;
      int row = t >> 2, s8 = (t & 3) * 8;
      GLL16(A + (size_t)(m0 + row) * K + k0 + s8, a_lds[nxt] + t * 8);
#pragma unroll
      for (int i = 0; i < 2; ++i) {
        int c = i * 256 + t;
        int rw = c >> 2, sb = (c & 3) * 8;
        GLL16(Wt + (size_t)(n0 + rw) * K + k0 + sb, b_lds[nxt] + c * 8);
      }
    }
    short8 af[2], bfr[4];
#pragma unroll
    for (int m = 0; m < 2; ++m)
      af[m] = *(const short8*)(a_lds[cur] + (wr + m * 16 + lr) * 32 + lk);
#pragma unroll
    for (int n = 0; n < 4; ++n)
      bfr[n] = *(const short8*)(b_lds[cur] + (wc + n * 16 + lr) * 32 + lk);
#pragma unroll
    for (int m = 0; m < 2; ++m)
#pragma unroll
      for (int n = 0; n < 4; ++n)
        acc[m][n] = __builtin_amdgcn_mfma_f32_16x16x32_bf16(af[m], bfr[n], acc[m][n], 0, 0, 0);
    __syncthreads();
    cur ^= 1;
  }

  int rb = (l >> 4) * 4;
#pragma unroll
  for (int n = 0; n < 4; ++n) {
    int col = n0 + wc + n * 16 + lr;
    float bv = bias[col];
#pragma unroll
    for (int m = 0; m < 2; ++m) {
#pragma unroll
      for (int r = 0; r < 4; ++r) {
        int row = m0 + wr + m * 16 + rb + r;
        float v = acc[m][n][r] + bv;
        if (RELU) v = fmaxf(v, 0.0f);
        if (OBF16) ((unsigned short*)Cout)[(size_t)row * N + col] = f2bf(v);
        else       ((float*)Cout)[(size_t)row * N + col] = v;
      }
    }
  }
}

// ---------------------------------------------------------------------------
// gemm_proj: fused offattn (N=384, A=qb, f32 out) + val (N=256, A=xb, bf16
// out). grid (170,5): by<3 -> offattn tile, by>=3 -> val tile. K=256.
// BK=32 double-buffered 2-phase, same body as gemm_tn.
// ---------------------------------------------------------------------------
__global__ __launch_bounds__(256) void gemm_proj(
    const unsigned short* __restrict__ qb, const unsigned short* __restrict__ xb,
    const unsigned short* __restrict__ wOA, const unsigned short* __restrict__ wV,
    const float* __restrict__ bOA, const float* __restrict__ bV,
    float* __restrict__ offat, unsigned short* __restrict__ vb) {
  __shared__ __align__(16) unsigned short a_lds[2][128 * 32];
  __shared__ __align__(16) unsigned short b_lds[2][128 * 32];
  const int K = 256;
  int by = blockIdx.y;
  bool isV = (by >= 3);
  const unsigned short* A  = isV ? xb : qb;
  const unsigned short* Wt = isV ? wV : wOA;
  const float* bias        = isV ? bV : bOA;
  int n0 = (isV ? (by - 3) : by) * 128;
  int m0 = blockIdx.x * 128;
  int t = threadIdx.x;
  int w = t >> 6, l = t & 63;
  int wr = (w >> 1) * 64, wc = (w & 1) * 64;
  int lr = l & 15, lk = (l >> 4) * 8;

  f32x4 acc[4][4] = {};
  const int nt = 8;
  int cur = 0;

#pragma unroll
  for (int i = 0; i < 2; ++i) {
    int c = i * 256 + t;
    int row = c >> 2, s8 = (c & 3) * 8;
    GLL16(A + (size_t)(m0 + row) * K + s8, a_lds[0] + c * 8);
  }
#pragma unroll
  for (int i = 0; i < 2; ++i) {
    int c = i * 256 + t;
    int row = c >> 2, s8 = (c & 3) * 8;
    GLL16(Wt + (size_t)(n0 + row) * K + s8, b_lds[0] + c * 8);
  }
  __syncthreads();

  for (int tt = 0; tt < nt; ++tt) {
    if (tt + 1 < nt) {
      int k0 = (tt + 1) << 5;
      int nxt = cur ^ 1;
#pragma unroll
      for (int i = 0; i < 2; ++i) {
        int c = i * 256 + t;
        int row = c >> 2, s8 = (c & 3) * 8;
        GLL16(A + (size_t)(m0 + row) * K + k0 + s8, a_lds[nxt] + c * 8);
      }
#pragma unroll
      for (int i = 0; i < 2; ++i) {
        int c = i * 256 + t;
        int row = c >> 2, s8 = (c & 3) * 8;
        GLL16(Wt + (size_t)(n0 + row) * K + k0 + s8, b_lds[nxt] + c * 8);
      }
    }
    short8 af[4], bfr[4];
#pragma unroll
    for (int m = 0; m < 4; ++m)
      af[m] = *(const short8*)(a_lds[cur] + (wr + m * 16 + lr) * 32 + lk);
#pragma unroll
    for (int n = 0; n < 4; ++n)
      bfr[n] = *(const short8*)(b_lds[cur] + (wc + n * 16 + lr) * 32 + lk);
#pragma unroll
    for (int m = 0; m < 4; ++m)
#pragma unroll
      for (int n = 0; n < 4; ++n)
        acc[m][n] = __builtin_amdgcn_mfma_f32_16x16x32_bf16(af[m], bfr[n], acc[m][n], 0, 0, 0);
    __syncthreads();
    cur ^= 1;
  }

  int rb = (l >> 4) * 4;
#pragma unroll
  for (int n = 0; n < 4; ++n) {
    int col = n0 + wc + n * 16 + lr;
    float bv = bias[col];
#pragma unroll
    for (int m = 0; m < 4; ++m) {
#pragma unroll
      for (int r = 0; r < 4; ++r) {
        int row = m0 + wr + m * 16 + rb + r;
        float v = acc[m][n][r] + bv;
        if (isV) vb[(size_t)row * 256 + col] = f2bf(v);
        else     offat[(size_t)row * 384 + col] = v;
      }
    }
  }
}

// ---------------------------------------------------------------------------
// deformable sampling v5: as v4 but with sched_barrier(0) fences forcing the
// descriptor-batch / gather-batch / math-batch separation at codegen level
// (v4's source-level batch was re-serialized by the scheduler: VGPR=32).
// __launch_bounds__(256,4) permits <=128 VGPR.
// ---------------------------------------------------------------------------
__global__ __launch_bounds__(256, 4) void ms_sample(
    const float* __restrict__ offattn, const unsigned short* __restrict__ vb,
    unsigned short* __restrict__ samp) {
  __shared__ __align__(16) uint2 sWI[512];   // [h][64 slots] (w bits, byte idx)
  int bid = blockIdx.x;
  int bl = (bid & 7) * (NTOK / 8) + (bid >> 3);   // XCD-contiguous tokens
  int t = threadIdx.x;
  int l = bl % LTOT;
  int bbase = (bl - l) * 256;              // b*L*256 (elements)
  if (t < 128) {
    float logit = offattn[(size_t)bl * 384 + 256 + t];
    float mx = logit;
#pragma unroll
    for (int o = 1; o < 16; o <<= 1) mx = fmaxf(mx, __shfl_xor(mx, o));
    float e = __expf(logit - mx);
    float ssum = e;
#pragma unroll
    for (int o = 1; o < 16; o <<= 1) ssum += __shfl_xor(ssum, o);
    float aw = e / ssum;

    int lev = (t >> 2) & 3;
    int lev_q = (l < 64) ? 0 : (l < 320) ? 1 : (l < 1344) ? 2 : 3;
    int start_q = (lev_q == 0) ? 0 : (lev_q == 1) ? 64 : (lev_q == 2) ? 320 : 1344;
    int shq = lev_q + 3;
    int r = l - start_q;
    int Wq = 1 << shq;
    int iy = r >> shq, ix = r & (Wq - 1);
    float invWq = 1.0f / (float)Wq;
    float refx = ((float)ix + 0.5f) * invWq;
    float refy = ((float)iy + 0.5f) * invWq;
    int iW = 8 << lev;
    float Wl = (float)iW;
    int start_l = (lev == 0) ? 0 : (lev == 1) ? 64 : (lev == 2) ? 320 : 1344;
    float ox = offattn[(size_t)bl * 384 + 2 * t];
    float oy = offattn[(size_t)bl * 384 + 2 * t + 1];
    float gx = refx * Wl + ox - 0.5f;
    float gy = refy * Wl + oy - 0.5f;
    float flx = floorf(gx), fly = floorf(gy);
    int x0 = (int)flx, y0 = (int)fly;
    float fx = gx - flx, fy = gy - fly;
#pragma unroll
    for (int c = 0; c < 4; ++c) {
      int cx = x0 + (c & 1);
      int cy = y0 + (c >> 1);
      int inb = (cx >= 0) && (cx < iW) && (cy >= 0) && (cy < iW);
      int cxc = cx < 0 ? 0 : (cx > iW - 1 ? iW - 1 : cx);
      int cyc = cy < 0 ? 0 : (cy > iW - 1 ? iW - 1 : cy);
      float wx = (c & 1) ? fx : 1.0f - fx;
      float wy = (c & 2) ? fy : 1.0f - fy;
      float wgt = inb ? aw * wx * wy : 0.0f;
      unsigned int idxb = (unsigned int)(start_l + cyc * iW + cxc) * 512u;  // bytes
      sWI[t * 4 + c] = make_uint2(__float_as_uint(wgt), idxb);
    }
  }
  __syncthreads();
  int h = t >> 5, j = t & 31;
  int q = j >> 3, p = j & 7;
  int rotp = ((h & 1) << 2) | q;                 // 8 distinct per wave
  const uint2* wiBase = sWI + h * 64 + q * 16;
  unsigned int chb = (unsigned int)(h * 32 + p * 4) * 2u;
  const char* vB = (const char*)(vb + bbase);
  // batch 1: all descriptors (8 x ds_read_b128)
  uint4 wi[8];
#pragma unroll
  for (int kp = 0; kp < 8; ++kp) {
    int kq = ((kp + rotp) & 7) * 2;
    wi[kp] = *(const uint4*)(wiBase + kq);
  }
  __builtin_amdgcn_sched_barrier(0);
  // batch 2: all 16 gathers issued back-to-back (true MLP)
  uint2 u0[8], u1[8];
#pragma unroll
  for (int kp = 0; kp < 8; ++kp) {
    u0[kp] = *(const uint2*)(vB + (wi[kp].y + chb));
    u1[kp] = *(const uint2*)(vB + (wi[kp].w + chb));
  }
  __builtin_amdgcn_sched_barrier(0);
  // batch 3: packed accumulation
  f32x2 a01 = {0.0f, 0.0f}, a23 = {0.0f, 0.0f};
#pragma unroll
  for (int kp = 0; kp < 8; ++kp) {
    float w0 = __uint_as_float(wi[kp].x);
    float w1 = __uint_as_float(wi[kp].z);
    f32x2 w0v = {w0, w0}, w1v = {w1, w1};
    f32x2 va = { __uint_as_float(u0[kp].x << 16), __uint_as_float(u0[kp].x & 0xffff0000u) };
    f32x2 vbv = { __uint_as_float(u0[kp].y << 16), __uint_as_float(u0[kp].y & 0xffff0000u) };
    a01 = __builtin_elementwise_fma(w0v, va, a01);
    a23 = __builtin_elementwise_fma(w0v, vbv, a23);
    f32x2 vc = { __uint_as_float(u1[kp].x << 16), __uint_as_float(u1[kp].x & 0xffff0000u) };
    f32x2 vd = { __uint_as_float(u1[kp].y << 16), __uint_as_float(u1[kp].y & 0xffff0000u) };
    a01 = __builtin_elementwise_fma(w1v, vc, a01);
    a23 = __builtin_elementwise_fma(w1v, vd, a23);
  }
  float c0 = a01.x, c1 = a01.y, c2 = a23.x, c3 = a23.y;
  c0 += __shfl_xor(c0, 8);  c1 += __shfl_xor(c1, 8);
  c2 += __shfl_xor(c2, 8);  c3 += __shfl_xor(c3, 8);
  c0 += __shfl_xor(c0, 16); c1 += __shfl_xor(c1, 16);
  c2 += __shfl_xor(c2, 16); c3 += __shfl_xor(c3, 16);
  if (q == 0) {
    uint2 pk;
    pk.x = (unsigned int)f2bf(c0) | ((unsigned int)f2bf(c1) << 16);
    pk.y = (unsigned int)f2bf(c2) | ((unsigned int)f2bf(c3) << 16);
    *(uint2*)(samp + (size_t)bl * 256 + h * 32 + p * 4) = pk;
  }
}

// x' = LN(x + y); writes f32 + bf16 shadow; QADD: also qb = bf16(x' + pos + lev_emb)
template<bool QADD>
__global__ __launch_bounds__(256) void ln_fused(
    const float* __restrict__ xin, const float* __restrict__ yin,
    const float* __restrict__ g, const float* __restrict__ bb,
    const float* __restrict__ pos, const float* __restrict__ lev_emb,
    float* __restrict__ xout, unsigned short* __restrict__ xbout,
    unsigned short* __restrict__ qbout) {
  int row = blockIdx.x * 4 + (threadIdx.x >> 6);
  int lane = threadIdx.x & 63;
  size_t base = (size_t)row * 64 + lane;   // float4 units
  float4 xv = ((const float4*)xin)[base];
  float4 yv = ((const float4*)yin)[base];
  float4 tv;
  tv.x = xv.x + yv.x; tv.y = xv.y + yv.y; tv.z = xv.z + yv.z; tv.w = xv.w + yv.w;
  float s = tv.x + tv.y + tv.z + tv.w;
  float s2 = tv.x * tv.x + tv.y * tv.y + tv.z * tv.z + tv.w * tv.w;
#pragma unroll
  for (int o = 1; o < 64; o <<= 1) {
    s += __shfl_xor(s, o, 64);
    s2 += __shfl_xor(s2, o, 64);
  }
  float mean = s * (1.0f / 256.0f);
  float var = s2 * (1.0f / 256.0f) - mean * mean;
  float rstd = rsqrtf(var + 1e-5f);
  float4 gv = ((const float4*)g)[lane];
  float4 bv = ((const float4*)bb)[lane];
  float4 o;
  o.x = gv.x * (tv.x - mean) * rstd + bv.x;
  o.y = gv.y * (tv.y - mean) * rstd + bv.y;
  o.z = gv.z * (tv.z - mean) * rstd + bv.z;
  o.w = gv.w * (tv.w - mean) * rstd + bv.w;
  ((float4*)xout)[base] = o;
  ushort4 ob;
  ob.x = f2bf(o.x); ob.y = f2bf(o.y); ob.z = f2bf(o.z); ob.w = f2bf(o.w);
  ((ushort4*)xbout)[base] = ob;
  if (QADD) {
    int tok = row % LTOT;
    int lev = (tok < 64) ? 0 : (tok < 320) ? 1 : (tok < 1344) ? 2 : 3;
    float4 pv = ((const float4*)pos)[base];
    float4 lv = ((const float4*)lev_emb)[lev * 64 + lane];
    ushort4 q;
    q.x = f2bf(o.x + pv.x + lv.x);
    q.y = f2bf(o.y + pv.y + lv.y);
    q.z = f2bf(o.z + pv.z + lv.z);
    q.w = f2bf(o.w + pv.w + lv.w);
    ((ushort4*)qbout)[base] = q;
  }
}

extern "C" void kernel_launch(void* const* d_in, const int* in_sizes, int n_in,
                              void* d_out, int out_size, void* d_ws, size_t ws_size,
                              hipStream_t stream) {
  (void)in_sizes; (void)n_in; (void)out_size; (void)ws_size;
  const float* src     = (const float*)d_in[0];
  const float* pos     = (const float*)d_in[1];
  const float* lev_emb = (const float*)d_in[2];
  const float* w_off   = (const float*)d_in[3];
  const float* b_off   = (const float*)d_in[4];
  const float* w_attn  = (const float*)d_in[5];
  const float* b_attn  = (const float*)d_in[6];
  const float* w_val   = (const float*)d_in[7];
  const float* b_val   = (const float*)d_in[8];
  const float* w_out   = (const float*)d_in[9];
  const float* b_out   = (const float*)d_in[10];
  const float* ln1_g   = (const float*)d_in[11];
  const float* ln1_b   = (const float*)d_in[12];
  const float* w_ff1   = (const float*)d_in[13];
  const float* b_ff1   = (const float*)d_in[14];
  const float* w_ff2   = (const float*)d_in[15];
  const float* b_ff2   = (const float*)d_in[16];
  const float* ln2_g   = (const float*)d_in[17];
  const float* ln2_b   = (const float*)d_in[18];

  char* ws = (char*)d_ws;
  float*          x     = (float*)(ws + 0);
  float*          y     = (float*)(ws + 22282240);
  unsigned short* xb    = (unsigned short*)(ws + 44564480);
  unsigned short* qb    = (unsigned short*)(ws + 55705600);  // aliased w/ sampb
  unsigned short* sampb = (unsigned short*)(ws + 55705600);  // (disjoint lifetimes)
  float*          offat = (float*)(ws + 66846720);           // [NTOK][384]
  unsigned short* vb    = (unsigned short*)(ws + 100270080);
  unsigned short* h1    = (unsigned short*)(ws + 66846720);  // alias offat+vb
  unsigned short* wT    = (unsigned short*)(ws + 111411200);
  float*          fb    = (float*)(ws + 120455168);          // fused bias [6][384]

  wconv<<<17664, 256, 0, stream>>>(w_off, w_attn, w_val, w_out, w_ff1, w_ff2, wT);
  bpack<<<6, 384, 0, stream>>>(b_off, b_attn, fb);
  prep<<<5440, 256, 0, stream>>>(src, pos, lev_emb, x, xb, qb);

  for (int i = 0; i < 6; ++i) {
    const unsigned short* wl = wT + (size_t)i * 753664;
    // fused offattn (N=384) + val (N=256) projections: 850 blocks
    gemm_proj<<<dim3(170, 5), 256, 0, stream>>>(qb, xb, wl + 0, wl + 98304,
                                                fb + i * 384, b_val + i * 256,
                                                offat, vb);
    ms_sample<<<NTOK, 256, 0, stream>>>(offat, vb, sampb);
    gemm_tn64<false, false><<<dim3(340, 2), 256, 0, stream>>>(sampb, wl + 163840, b_out + i * 256, (void*)y, NTOK, 256, 256);
    ln_fused<false><<<5440, 256, 0, stream>>>(x, y, ln1_g + i * 256, ln1_b + i * 256, pos, lev_emb, x, xb, qb);
    gemm_tn<true, true ><<<dim3(170, 8), 256, 0, stream>>>(xb, wl + 229376, b_ff1 + i * 1024, (void*)h1, NTOK, 1024, 256);
    gemm_tn64<false, false><<<dim3(340, 2), 256, 0, stream>>>(h1, wl + 491520, b_ff2 + i * 256, (void*)y, NTOK, 256, 1024);
    float* xo = (i == 5) ? (float*)d_out : x;
    if (i < 5)
      ln_fused<true ><<<5440, 256, 0, stream>>>(x, y, ln2_g + i * 256, ln2_b + i * 256, pos, lev_emb, xo, xb, qb);
    else
      ln_fused<false><<<5440, 256, 0, stream>>>(x, y, ln2_g + i * 256, ln2_b + i * 256, pos, lev_emb, xo, xb, qb);
  }
}

// Round 9
// 1168.890 us; speedup vs baseline: 1.0764x; 1.0764x over previous
//
#include <hip/hip_runtime.h>

#define LTOT 5440
#define NTOK 21760   // B*L = 4*5440

typedef float  f32x4  __attribute__((ext_vector_type(4)));
typedef float  f32x2  __attribute__((ext_vector_type(2)));
typedef short  short8 __attribute__((ext_vector_type(8)));

__device__ __forceinline__ unsigned short f2bf(float f) {
  unsigned int u = __float_as_uint(f);
  u += 0x7FFF + ((u >> 16) & 1);          // RNE
  return (unsigned short)(u >> 16);
}
__device__ __forceinline__ float bf2f(unsigned short u) {
  return __uint_as_float(((unsigned int)u) << 16);
}

#define GLL16(gp, lp) __builtin_amdgcn_global_load_lds( \
    (const __attribute__((address_space(1))) void*)(gp), \
    (__attribute__((address_space(3))) void*)(lp), 16, 0, 0)

// ---------------------------------------------------------------------------
// Weight convert+transpose: all six weight kinds, all 6 layers -> bf16 [N][K]
// per-layer (elements): off[256][256]@0, attn[128][256]@65536  (together =
// fused offattn [384][256]@0), val[256][256]@98304, out[256][256]@163840,
// ff1[1024][256]@229376, ff2[256][1024]@491520 ; layer stride 753664.
// ---------------------------------------------------------------------------
__global__ void wconv(const float* __restrict__ w_off, const float* __restrict__ w_attn,
                      const float* __restrict__ w_val, const float* __restrict__ w_out,
                      const float* __restrict__ w_ff1, const float* __restrict__ w_ff2,
                      unsigned short* __restrict__ dst) {
  int tid = blockIdx.x * 256 + threadIdx.x;
  const int PER = 753664;
  if (tid >= 6 * PER) return;
  int layer = tid / PER;
  int rem = tid - layer * PER;
  int base, K, N;
  const float* src;
  if (rem < 65536)       { base = 0;      K = 256;  N = 256;  src = w_off; }
  else if (rem < 98304)  { base = 65536;  K = 256;  N = 128;  src = w_attn; }
  else if (rem < 163840) { base = 98304;  K = 256;  N = 256;  src = w_val; }
  else if (rem < 229376) { base = 163840; K = 256;  N = 256;  src = w_out; }
  else if (rem < 491520) { base = 229376; K = 256;  N = 1024; src = w_ff1; }
  else                   { base = 491520; K = 1024; N = 256;  src = w_ff2; }
  int local = rem - base;
  int n = local / K, k = local - n * K;
  dst[tid] = f2bf(src[(size_t)layer * K * N + (size_t)k * N + n]);
}

// pack fused off+attn bias: fb[layer][384]
__global__ void bpack(const float* __restrict__ b_off, const float* __restrict__ b_attn,
                      float* __restrict__ fb) {
  int l = blockIdx.x, t = threadIdx.x;
  fb[l * 384 + t] = (t < 256) ? b_off[l * 256 + t] : b_attn[l * 128 + t - 256];
}

// x = src (f32 master) + bf16 shadow + qb = bf16(src + pos + lev_emb)
__global__ void prep(const float* __restrict__ src, const float* __restrict__ pos,
                     const float* __restrict__ lev_emb, float* __restrict__ x,
                     unsigned short* __restrict__ xb, unsigned short* __restrict__ qb) {
  int i = blockIdx.x * 256 + threadIdx.x;   // float4 index, NTOK*64 total
  int d4 = i & 63;
  int tok = (i >> 6) % LTOT;
  int lev = (tok < 64) ? 0 : (tok < 320) ? 1 : (tok < 1344) ? 2 : 3;
  float4 s = ((const float4*)src)[i];
  float4 pv = ((const float4*)pos)[i];
  float4 lv = ((const float4*)lev_emb)[lev * 64 + d4];
  ((float4*)x)[i] = s;
  ushort4 o;
  o.x = f2bf(s.x); o.y = f2bf(s.y); o.z = f2bf(s.z); o.w = f2bf(s.w);
  ((ushort4*)xb)[i] = o;
  ushort4 q;
  q.x = f2bf(s.x + pv.x + lv.x);
  q.y = f2bf(s.y + pv.y + lv.y);
  q.z = f2bf(s.z + pv.z + lv.z);
  q.w = f2bf(s.w + pv.w + lv.w);
  ((ushort4*)qb)[i] = q;
}

// ---------------------------------------------------------------------------
// bf16 MFMA GEMM, C = A[M][K] * Wt[N][K]^T + bias.  TN, 128x128 tile, BK=32,
// double-buffered 2-phase. LDS 32KB. 4 waves 2x2.
// ---------------------------------------------------------------------------
template<bool RELU, bool OBF16>
__global__ __launch_bounds__(256) void gemm_tn(
    const unsigned short* __restrict__ A, const unsigned short* __restrict__ Wt,
    const float* __restrict__ bias, void* __restrict__ Cout,
    int M, int N, int K) {
  __shared__ __align__(16) unsigned short a_lds[2][128 * 32];
  __shared__ __align__(16) unsigned short b_lds[2][128 * 32];
  int m0 = blockIdx.x * 128;
  int n0 = blockIdx.y * 128;
  int t = threadIdx.x;
  int w = t >> 6, l = t & 63;
  int wr = (w >> 1) * 64, wc = (w & 1) * 64;
  int lr = l & 15, lk = (l >> 4) * 8;

  f32x4 acc[4][4] = {};
  int nt = K >> 5;
  int cur = 0;

#pragma unroll
  for (int i = 0; i < 2; ++i) {
    int c = i * 256 + t;
    int row = c >> 2, s8 = (c & 3) * 8;
    GLL16(A + (size_t)(m0 + row) * K + s8, a_lds[0] + c * 8);
  }
#pragma unroll
  for (int i = 0; i < 2; ++i) {
    int c = i * 256 + t;
    int row = c >> 2, s8 = (c & 3) * 8;
    GLL16(Wt + (size_t)(n0 + row) * K + s8, b_lds[0] + c * 8);
  }
  __syncthreads();

  for (int tt = 0; tt < nt; ++tt) {
    if (tt + 1 < nt) {
      int k0 = (tt + 1) << 5;
      int nxt = cur ^ 1;
#pragma unroll
      for (int i = 0; i < 2; ++i) {
        int c = i * 256 + t;
        int row = c >> 2, s8 = (c & 3) * 8;
        GLL16(A + (size_t)(m0 + row) * K + k0 + s8, a_lds[nxt] + c * 8);
      }
#pragma unroll
      for (int i = 0; i < 2; ++i) {
        int c = i * 256 + t;
        int row = c >> 2, s8 = (c & 3) * 8;
        GLL16(Wt + (size_t)(n0 + row) * K + k0 + s8, b_lds[nxt] + c * 8);
      }
    }
    short8 af[4], bfr[4];
#pragma unroll
    for (int m = 0; m < 4; ++m)
      af[m] = *(const short8*)(a_lds[cur] + (wr + m * 16 + lr) * 32 + lk);
#pragma unroll
    for (int n = 0; n < 4; ++n)
      bfr[n] = *(const short8*)(b_lds[cur] + (wc + n * 16 + lr) * 32 + lk);
#pragma unroll
    for (int m = 0; m < 4; ++m)
#pragma unroll
      for (int n = 0; n < 4; ++n)
        acc[m][n] = __builtin_amdgcn_mfma_f32_16x16x32_bf16(af[m], bfr[n], acc[m][n], 0, 0, 0);
    __syncthreads();
    cur ^= 1;
  }

  int rb = (l >> 4) * 4;
#pragma unroll
  for (int n = 0; n < 4; ++n) {
    int col = n0 + wc + n * 16 + lr;
    float bv = bias[col];
#pragma unroll
    for (int m = 0; m < 4; ++m) {
#pragma unroll
      for (int r = 0; r < 4; ++r) {
        int row = m0 + wr + m * 16 + rb + r;
        float v = acc[m][n][r] + bv;
        if (RELU) v = fmaxf(v, 0.0f);
        if (OBF16) ((unsigned short*)Cout)[(size_t)row * N + col] = f2bf(v);
        else       ((float*)Cout)[(size_t)row * N + col] = v;
      }
    }
  }
}

// ---------------------------------------------------------------------------
// gemm_tn64: BM=64 x BN=128, BK=32 double-buffered (24KB LDS).
// grid (340,2) for N=256 outputs. 4 waves 2x2, each 32x64 out.
// ---------------------------------------------------------------------------
template<bool RELU, bool OBF16>
__global__ __launch_bounds__(256) void gemm_tn64(
    const unsigned short* __restrict__ A, const unsigned short* __restrict__ Wt,
    const float* __restrict__ bias, void* __restrict__ Cout,
    int M, int N, int K) {
  __shared__ __align__(16) unsigned short a_lds[2][64 * 32];
  __shared__ __align__(16) unsigned short b_lds[2][128 * 32];
  int m0 = blockIdx.x * 64;
  int n0 = blockIdx.y * 128;
  int t = threadIdx.x;
  int w = t >> 6, l = t & 63;
  int wr = (w >> 1) * 32, wc = (w & 1) * 64;
  int lr = l & 15, lk = (l >> 4) * 8;

  f32x4 acc[2][4] = {};
  int nt = K >> 5;
  int cur = 0;

  {
    int row = t >> 2, s8 = (t & 3) * 8;
    GLL16(A + (size_t)(m0 + row) * K + s8, a_lds[0] + t * 8);
#pragma unroll
    for (int i = 0; i < 2; ++i) {
      int c = i * 256 + t;
      int rw = c >> 2, sb = (c & 3) * 8;
      GLL16(Wt + (size_t)(n0 + rw) * K + sb, b_lds[0] + c * 8);
    }
  }
  __syncthreads();

  for (int tt = 0; tt < nt; ++tt) {
    if (tt + 1 < nt) {
      int k0 = (tt + 1) << 5;
      int nxt = cur ^ 1;
      int row = t >> 2, s8 = (t & 3) * 8;
      GLL16(A + (size_t)(m0 + row) * K + k0 + s8, a_lds[nxt] + t * 8);
#pragma unroll
      for (int i = 0; i < 2; ++i) {
        int c = i * 256 + t;
        int rw = c >> 2, sb = (c & 3) * 8;
        GLL16(Wt + (size_t)(n0 + rw) * K + k0 + sb, b_lds[nxt] + c * 8);
      }
    }
    short8 af[2], bfr[4];
#pragma unroll
    for (int m = 0; m < 2; ++m)
      af[m] = *(const short8*)(a_lds[cur] + (wr + m * 16 + lr) * 32 + lk);
#pragma unroll
    for (int n = 0; n < 4; ++n)
      bfr[n] = *(const short8*)(b_lds[cur] + (wc + n * 16 + lr) * 32 + lk);
#pragma unroll
    for (int m = 0; m < 2; ++m)
#pragma unroll
      for (int n = 0; n < 4; ++n)
        acc[m][n] = __builtin_amdgcn_mfma_f32_16x16x32_bf16(af[m], bfr[n], acc[m][n], 0, 0, 0);
    __syncthreads();
    cur ^= 1;
  }

  int rb = (l >> 4) * 4;
#pragma unroll
  for (int n = 0; n < 4; ++n) {
    int col = n0 + wc + n * 16 + lr;
    float bv = bias[col];
#pragma unroll
    for (int m = 0; m < 2; ++m) {
#pragma unroll
      for (int r = 0; r < 4; ++r) {
        int row = m0 + wr + m * 16 + rb + r;
        float v = acc[m][n][r] + bv;
        if (RELU) v = fmaxf(v, 0.0f);
        if (OBF16) ((unsigned short*)Cout)[(size_t)row * N + col] = f2bf(v);
        else       ((float*)Cout)[(size_t)row * N + col] = v;
      }
    }
  }
}

// ---------------------------------------------------------------------------
// gemm_proj: fused offattn (N=384, A=qb, f32 out) + val (N=256, A=xb, bf16
// out). grid (170,5): by<3 -> offattn tile, by>=3 -> val tile. K=256.
// BK=32 double-buffered, same body as gemm_tn.
// ---------------------------------------------------------------------------
__global__ __launch_bounds__(256) void gemm_proj(
    const unsigned short* __restrict__ qb, const unsigned short* __restrict__ xb,
    const unsigned short* __restrict__ wOA, const unsigned short* __restrict__ wV,
    const float* __restrict__ bOA, const float* __restrict__ bV,
    float* __restrict__ offat, unsigned short* __restrict__ vb) {
  __shared__ __align__(16) unsigned short a_lds[2][128 * 32];
  __shared__ __align__(16) unsigned short b_lds[2][128 * 32];
  const int K = 256;
  int by = blockIdx.y;
  bool isV = (by >= 3);
  const unsigned short* A  = isV ? xb : qb;
  const unsigned short* Wt = isV ? wV : wOA;
  const float* bias        = isV ? bV : bOA;
  int n0 = (isV ? (by - 3) : by) * 128;
  int m0 = blockIdx.x * 128;
  int t = threadIdx.x;
  int w = t >> 6, l = t & 63;
  int wr = (w >> 1) * 64, wc = (w & 1) * 64;
  int lr = l & 15, lk = (l >> 4) * 8;

  f32x4 acc[4][4] = {};
  const int nt = 8;
  int cur = 0;

#pragma unroll
  for (int i = 0; i < 2; ++i) {
    int c = i * 256 + t;
    int row = c >> 2, s8 = (c & 3) * 8;
    GLL16(A + (size_t)(m0 + row) * K + s8, a_lds[0] + c * 8);
  }
#pragma unroll
  for (int i = 0; i < 2; ++i) {
    int c = i * 256 + t;
    int row = c >> 2, s8 = (c & 3) * 8;
    GLL16(Wt + (size_t)(n0 + row) * K + s8, b_lds[0] + c * 8);
  }
  __syncthreads();

  for (int tt = 0; tt < nt; ++tt) {
    if (tt + 1 < nt) {
      int k0 = (tt + 1) << 5;
      int nxt = cur ^ 1;
#pragma unroll
      for (int i = 0; i < 2; ++i) {
        int c = i * 256 + t;
        int row = c >> 2, s8 = (c & 3) * 8;
        GLL16(A + (size_t)(m0 + row) * K + k0 + s8, a_lds[nxt] + c * 8);
      }
#pragma unroll
      for (int i = 0; i < 2; ++i) {
        int c = i * 256 + t;
        int row = c >> 2, s8 = (c & 3) * 8;
        GLL16(Wt + (size_t)(n0 + row) * K + k0 + s8, b_lds[nxt] + c * 8);
      }
    }
    short8 af[4], bfr[4];
#pragma unroll
    for (int m = 0; m < 4; ++m)
      af[m] = *(const short8*)(a_lds[cur] + (wr + m * 16 + lr) * 32 + lk);
#pragma unroll
    for (int n = 0; n < 4; ++n)
      bfr[n] = *(const short8*)(b_lds[cur] + (wc + n * 16 + lr) * 32 + lk);
#pragma unroll
    for (int m = 0; m < 4; ++m)
#pragma unroll
      for (int n = 0; n < 4; ++n)
        acc[m][n] = __builtin_amdgcn_mfma_f32_16x16x32_bf16(af[m], bfr[n], acc[m][n], 0, 0, 0);
    __syncthreads();
    cur ^= 1;
  }

  int rb = (l >> 4) * 4;
#pragma unroll
  for (int n = 0; n < 4; ++n) {
    int col = n0 + wc + n * 16 + lr;
    float bv = bias[col];
#pragma unroll
    for (int m = 0; m < 4; ++m) {
#pragma unroll
      for (int r = 0; r < 4; ++r) {
        int row = m0 + wr + m * 16 + rb + r;
        float v = acc[m][n][r] + bv;
        if (isV) vb[(size_t)row * 256 + col] = f2bf(v);
        else     offat[(size_t)row * 384 + col] = v;
      }
    }
  }
}

// ---------------------------------------------------------------------------
// deformable sampling v4 (reverted known-good): fused softmax, bf16 v, XCD-
// swizzled blocks. phase1 (t<128): softmax 16-group via shfl; (w, byte-idx)
// uint2 into LDS. phase2: t=h*32+j; q=j>>3 owns 16 slots, p=j&7 -> 4 chans.
// ds_read_b128 = 2 slots; rotation rotp decollides broadcast banks.
// ---------------------------------------------------------------------------
__global__ __launch_bounds__(256) void ms_sample(
    const float* __restrict__ offattn, const unsigned short* __restrict__ vb,
    unsigned short* __restrict__ samp) {
  __shared__ __align__(16) uint2 sWI[512];   // [h][64 slots] (w bits, byte idx)
  int bid = blockIdx.x;
  int bl = (bid & 7) * (NTOK / 8) + (bid >> 3);   // XCD-contiguous tokens
  int t = threadIdx.x;
  int l = bl % LTOT;
  int bbase = (bl - l) * 256;              // b*L*256 (elements)
  if (t < 128) {
    float logit = offattn[(size_t)bl * 384 + 256 + t];
    float mx = logit;
#pragma unroll
    for (int o = 1; o < 16; o <<= 1) mx = fmaxf(mx, __shfl_xor(mx, o));
    float e = __expf(logit - mx);
    float ssum = e;
#pragma unroll
    for (int o = 1; o < 16; o <<= 1) ssum += __shfl_xor(ssum, o);
    float aw = e / ssum;

    int lev = (t >> 2) & 3;
    int lev_q = (l < 64) ? 0 : (l < 320) ? 1 : (l < 1344) ? 2 : 3;
    int start_q = (lev_q == 0) ? 0 : (lev_q == 1) ? 64 : (lev_q == 2) ? 320 : 1344;
    int shq = lev_q + 3;
    int r = l - start_q;
    int Wq = 1 << shq;
    int iy = r >> shq, ix = r & (Wq - 1);
    float invWq = 1.0f / (float)Wq;
    float refx = ((float)ix + 0.5f) * invWq;
    float refy = ((float)iy + 0.5f) * invWq;
    int iW = 8 << lev;
    float Wl = (float)iW;
    int start_l = (lev == 0) ? 0 : (lev == 1) ? 64 : (lev == 2) ? 320 : 1344;
    float ox = offattn[(size_t)bl * 384 + 2 * t];
    float oy = offattn[(size_t)bl * 384 + 2 * t + 1];
    float gx = refx * Wl + ox - 0.5f;
    float gy = refy * Wl + oy - 0.5f;
    float flx = floorf(gx), fly = floorf(gy);
    int x0 = (int)flx, y0 = (int)fly;
    float fx = gx - flx, fy = gy - fly;
#pragma unroll
    for (int c = 0; c < 4; ++c) {
      int cx = x0 + (c & 1);
      int cy = y0 + (c >> 1);
      int inb = (cx >= 0) && (cx < iW) && (cy >= 0) && (cy < iW);
      int cxc = cx < 0 ? 0 : (cx > iW - 1 ? iW - 1 : cx);
      int cyc = cy < 0 ? 0 : (cy > iW - 1 ? iW - 1 : cy);
      float wx = (c & 1) ? fx : 1.0f - fx;
      float wy = (c & 2) ? fy : 1.0f - fy;
      float wgt = inb ? aw * wx * wy : 0.0f;
      unsigned int idxb = (unsigned int)(start_l + cyc * iW + cxc) * 512u;  // bytes
      sWI[t * 4 + c] = make_uint2(__float_as_uint(wgt), idxb);
    }
  }
  __syncthreads();
  int h = t >> 5, j = t & 31;
  int q = j >> 3, p = j & 7;
  int rotp = ((h & 1) << 2) | q;                 // 8 distinct per wave
  const uint2* wiBase = sWI + h * 64 + q * 16;
  unsigned int chb = (unsigned int)(h * 32 + p * 4) * 2u;
  const char* vB = (const char*)(vb + bbase);
  f32x2 a01 = {0.0f, 0.0f}, a23 = {0.0f, 0.0f};
#pragma unroll
  for (int kp = 0; kp < 8; ++kp) {
    int kq = ((kp + rotp) & 7) * 2;
    uint4 wi2 = *(const uint4*)(wiBase + kq);    // 2 slots: (w0,i0,w1,i1)
    float w0 = __uint_as_float(wi2.x);
    float w1 = __uint_as_float(wi2.z);
    uint2 u0 = *(const uint2*)(vB + (wi2.y + chb));
    uint2 u1 = *(const uint2*)(vB + (wi2.w + chb));
    f32x2 v01a = { __uint_as_float(u0.x << 16), __uint_as_float(u0.x & 0xffff0000u) };
    f32x2 v23a = { __uint_as_float(u0.y << 16), __uint_as_float(u0.y & 0xffff0000u) };
    f32x2 w0v = {w0, w0};
    a01 = __builtin_elementwise_fma(w0v, v01a, a01);
    a23 = __builtin_elementwise_fma(w0v, v23a, a23);
    f32x2 v01b = { __uint_as_float(u1.x << 16), __uint_as_float(u1.x & 0xffff0000u) };
    f32x2 v23b = { __uint_as_float(u1.y << 16), __uint_as_float(u1.y & 0xffff0000u) };
    f32x2 w1v = {w1, w1};
    a01 = __builtin_elementwise_fma(w1v, v01b, a01);
    a23 = __builtin_elementwise_fma(w1v, v23b, a23);
  }
  float c0 = a01.x, c1 = a01.y, c2 = a23.x, c3 = a23.y;
  c0 += __shfl_xor(c0, 8);  c1 += __shfl_xor(c1, 8);
  c2 += __shfl_xor(c2, 8);  c3 += __shfl_xor(c3, 8);
  c0 += __shfl_xor(c0, 16); c1 += __shfl_xor(c1, 16);
  c2 += __shfl_xor(c2, 16); c3 += __shfl_xor(c3, 16);
  if (q == 0) {
    uint2 pk;
    pk.x = (unsigned int)f2bf(c0) | ((unsigned int)f2bf(c1) << 16);
    pk.y = (unsigned int)f2bf(c2) | ((unsigned int)f2bf(c3) << 16);
    *(uint2*)(samp + (size_t)bl * 256 + h * 32 + p * 4) = pk;
  }
}

// x' = LN(x + y); y is bf16; writes f32 + bf16 shadow; QADD: also qb.
template<bool QADD>
__global__ __launch_bounds__(256) void ln_fused(
    const float* __restrict__ xin, const unsigned short* __restrict__ yin,
    const float* __restrict__ g, const float* __restrict__ bb,
    const float* __restrict__ pos, const float* __restrict__ lev_emb,
    float* __restrict__ xout, unsigned short* __restrict__ xbout,
    unsigned short* __restrict__ qbout) {
  int row = blockIdx.x * 4 + (threadIdx.x >> 6);
  int lane = threadIdx.x & 63;
  size_t base = (size_t)row * 64 + lane;   // float4 / ushort4 units
  float4 xv = ((const float4*)xin)[base];
  ushort4 yv = ((const ushort4*)yin)[base];
  float4 tv;
  tv.x = xv.x + bf2f(yv.x); tv.y = xv.y + bf2f(yv.y);
  tv.z = xv.z + bf2f(yv.z); tv.w = xv.w + bf2f(yv.w);
  float s = tv.x + tv.y + tv.z + tv.w;
  float s2 = tv.x * tv.x + tv.y * tv.y + tv.z * tv.z + tv.w * tv.w;
#pragma unroll
  for (int o = 1; o < 64; o <<= 1) {
    s += __shfl_xor(s, o, 64);
    s2 += __shfl_xor(s2, o, 64);
  }
  float mean = s * (1.0f / 256.0f);
  float var = s2 * (1.0f / 256.0f) - mean * mean;
  float rstd = rsqrtf(var + 1e-5f);
  float4 gv = ((const float4*)g)[lane];
  float4 bv = ((const float4*)bb)[lane];
  float4 o;
  o.x = gv.x * (tv.x - mean) * rstd + bv.x;
  o.y = gv.y * (tv.y - mean) * rstd + bv.y;
  o.z = gv.z * (tv.z - mean) * rstd + bv.z;
  o.w = gv.w * (tv.w - mean) * rstd + bv.w;
  ((float4*)xout)[base] = o;
  ushort4 ob;
  ob.x = f2bf(o.x); ob.y = f2bf(o.y); ob.z = f2bf(o.z); ob.w = f2bf(o.w);
  ((ushort4*)xbout)[base] = ob;
  if (QADD) {
    int tok = row % LTOT;
    int lev = (tok < 64) ? 0 : (tok < 320) ? 1 : (tok < 1344) ? 2 : 3;
    float4 pv = ((const float4*)pos)[base];
    float4 lv = ((const float4*)lev_emb)[lev * 64 + lane];
    ushort4 q;
    q.x = f2bf(o.x + pv.x + lv.x);
    q.y = f2bf(o.y + pv.y + lv.y);
    q.z = f2bf(o.z + pv.z + lv.z);
    q.w = f2bf(o.w + pv.w + lv.w);
    ((ushort4*)qbout)[base] = q;
  }
}

extern "C" void kernel_launch(void* const* d_in, const int* in_sizes, int n_in,
                              void* d_out, int out_size, void* d_ws, size_t ws_size,
                              hipStream_t stream) {
  (void)in_sizes; (void)n_in; (void)out_size; (void)ws_size;
  const float* src     = (const float*)d_in[0];
  const float* pos     = (const float*)d_in[1];
  const float* lev_emb = (const float*)d_in[2];
  const float* w_off   = (const float*)d_in[3];
  const float* b_off   = (const float*)d_in[4];
  const float* w_attn  = (const float*)d_in[5];
  const float* b_attn  = (const float*)d_in[6];
  const float* w_val   = (const float*)d_in[7];
  const float* b_val   = (const float*)d_in[8];
  const float* w_out   = (const float*)d_in[9];
  const float* b_out   = (const float*)d_in[10];
  const float* ln1_g   = (const float*)d_in[11];
  const float* ln1_b   = (const float*)d_in[12];
  const float* w_ff1   = (const float*)d_in[13];
  const float* b_ff1   = (const float*)d_in[14];
  const float* w_ff2   = (const float*)d_in[15];
  const float* b_ff2   = (const float*)d_in[16];
  const float* ln2_g   = (const float*)d_in[17];
  const float* ln2_b   = (const float*)d_in[18];

  char* ws = (char*)d_ws;
  float*          x     = (float*)(ws + 0);
  unsigned short* yb    = (unsigned short*)(ws + 22282240);  // bf16 branch out
  unsigned short* xb    = (unsigned short*)(ws + 44564480);
  unsigned short* qb    = (unsigned short*)(ws + 55705600);  // aliased w/ sampb
  unsigned short* sampb = (unsigned short*)(ws + 55705600);  // (disjoint lifetimes)
  float*          offat = (float*)(ws + 66846720);           // [NTOK][384]
  unsigned short* vb    = (unsigned short*)(ws + 100270080);
  unsigned short* h1    = (unsigned short*)(ws + 66846720);  // alias offat+vb
  unsigned short* wT    = (unsigned short*)(ws + 111411200);
  float*          fb    = (float*)(ws + 120455168);          // fused bias [6][384]

  wconv<<<17664, 256, 0, stream>>>(w_off, w_attn, w_val, w_out, w_ff1, w_ff2, wT);
  bpack<<<6, 384, 0, stream>>>(b_off, b_attn, fb);
  prep<<<5440, 256, 0, stream>>>(src, pos, lev_emb, x, xb, qb);

  for (int i = 0; i < 6; ++i) {
    const unsigned short* wl = wT + (size_t)i * 753664;
    gemm_proj<<<dim3(170, 5), 256, 0, stream>>>(qb, xb, wl + 0, wl + 98304,
                                                fb + i * 384, b_val + i * 256,
                                                offat, vb);
    ms_sample<<<NTOK, 256, 0, stream>>>(offat, vb, sampb);
    gemm_tn64<false, true ><<<dim3(340, 2), 256, 0, stream>>>(sampb, wl + 163840, b_out + i * 256, (void*)yb, NTOK, 256, 256);
    ln_fused<false><<<5440, 256, 0, stream>>>(x, yb, ln1_g + i * 256, ln1_b + i * 256, pos, lev_emb, x, xb, qb);
    gemm_tn<true, true ><<<dim3(170, 8), 256, 0, stream>>>(xb, wl + 229376, b_ff1 + i * 1024, (void*)h1, NTOK, 1024, 256);
    gemm_tn64<false, true ><<<dim3(340, 2), 256, 0, stream>>>(h1, wl + 491520, b_ff2 + i * 256, (void*)yb, NTOK, 256, 1024);
    float* xo = (i == 5) ? (float*)d_out : x;
    if (i < 5)
      ln_fused<true ><<<5440, 256, 0, stream>>>(x, yb, ln2_g + i * 256, ln2_b + i * 256, pos, lev_emb, xo, xb, qb);
    else
      ln_fused<false><<<5440, 256, 0, stream>>>(x, yb, ln2_g + i * 256, ln2_b + i * 256, pos, lev_emb, xo, xb, qb);
  }
}